// Round 11
// baseline (70.766 us; speedup 1.0000x reference)
//
#include <hip/hip_runtime.h>

// ToeplitzMemoryProjection (HiPPO LagT, alpha=0.5 bilinear).
//
// Recurrence (exact in the truncated lower-tri Toeplitz algebra, verified
// rounds 1-10): with c = 1+0.25dt, g = (1-0.25dt)/c, beta = dt*u/c,
//   x_l[i] = g_l*(x_l[i-1] + x_{l-1}[i]) - x_{l-1}[i-1] + beta_l*[i==0]
//
// R11 = R9 (best: 65.6us) + PRODUCER/CONSUMER WAVE SPLIT:
//  - 512-thread blocks, 256 blocks (1 channel each). Waves 0-3 = compute
//    (R9's exact chunk body, flush removed). Waves 4-7 = store waves.
//  - Store wave sw flushes compute wave sw's ring with LAG 96: rows
//    [bl-96, bl-65], fully written by end of phase c-1 (row bl-65 done at
//    tick T0-2), barrier-ordered. Residues mod 128: flush = bl+{32..63},
//    compute wave's phase-c writes = bl+{-63..+31} -> disjoint (R10 proof).
//  - Rationale: grid=256 means 1 wave/SIMD structurally; every serial
//    segment (32-tick dpp->fma chain, flush lgkm wait, stores) was fully
//    exposed, phase time = SUM of parts. With 8 waves/block (2/SIMD) the
//    store wave's waits/stores overlap the compute wave's tick chain ->
//    phase time -> max(compute, store).
//  - Barriers stay LDS-only (s_waitcnt lgkmcnt(0) + s_barrier, no vmcnt
//    drain): the nontemporal store stream stays in flight across phases.
//  - All LDS patterns at the conflict-free optimum (unchanged from R9).

namespace {

constexpr int LLEN   = 1024;
constexpr int NCHAN  = 256;
constexpr int KCH    = 32;                 // ticks per phase
constexpr int SKEW   = 96;                 // wave skew; 96-63=33 > KCH-1
constexpr int RSLOT  = 128;                // row slots per ring (pow2)
constexpr int NCHUNK = 44;                 // wave3 last flush F=992 @ T0=1376
constexpr int GPAD   = 1152;               // g/b padded length

constexpr int G_OFF = 0;
constexpr int B_OFF = GPAD;
constexpr int R_OFF = 2 * GPAD;
constexpr int LDS_FLOATS = R_OFF + 4 * RSLOT * 64;
constexpr size_t LDS_BYTES = (size_t)LDS_FLOATS * 4;   // 140288 B

using f32x4 = __attribute__((ext_vector_type(4))) float;

__device__ __forceinline__ float dpp_shr1(float v) {
    // lane i <- lane i-1; lane 0 <- 0
    return __int_as_float(__builtin_amdgcn_update_dpp(
        0, __float_as_int(v), 0x138 /*WAVE_SHR1*/, 0xF, 0xF, false));
}

// LDS-only barrier: orders ring handoffs without draining the store queue.
__device__ __forceinline__ void lds_barrier() {
    __builtin_amdgcn_sched_barrier(0);
    asm volatile("s_waitcnt lgkmcnt(0)" ::: "memory");
    __builtin_amdgcn_s_barrier();
    __builtin_amdgcn_sched_barrier(0);
}

// One 32-tick chunk (R9's proven body, flush removed).
// hb source: W0 -> b_arr (beta, aligned b128); else -> left wave's ring
// col 63 at slot (row & 127).
template <bool W0, bool MASKED>
__device__ __forceinline__ void do_chunk(
    const int T0, const int bl, const int lane, const bool lane0,
    const float* __restrict__ g_arr, const float* __restrict__ hb_src,
    float* __restrict__ my_ring, float& prev_own, float& prev_left)
{
    float hb[KCH];
    if (W0) {
        #pragma unroll
        for (int q = 0; q < KCH / 4; ++q) {
            const f32x4 t =
                *reinterpret_cast<const f32x4*>(hb_src + T0 + 4 * q);
            hb[4*q+0] = t[0]; hb[4*q+1] = t[1];
            hb[4*q+2] = t[2]; hb[4*q+3] = t[3];
        }
    } else {
        #pragma unroll
        for (int s = 0; s < KCH; ++s)
            hb[s] = hb_src[(((bl + s) & (RSLOT - 1)) << 6) + 63];
    }

    const int m0 = bl - lane;              // this lane's row at s=0
    #pragma unroll
    for (int s = 0; s < KCH; ++s) {
        int li = m0 + s;
        if (MASKED) li = min(max(li, 0), LLEN - 1);
        const float gg = g_arr[li];
        float cl = dpp_shr1(prev_own);
        float ct;
        if (W0) {
            ct = (lane0 ? hb[s] : 0.0f) - prev_left;   // lane0: +beta
        } else {
            cl += lane0 ? hb[s] : 0.0f;                // lane0: handoff
            ct = 0.0f - prev_left;
        }
        const float x = fmaf(gg, cl, fmaf(gg, prev_own, ct));
        my_ring[(((m0 + s) & (RSLOT - 1)) << 6) + lane] = x;
        if (MASKED) {
            const bool act = (unsigned)(m0 + s) < (unsigned)LLEN;
            prev_left = act ? cl : prev_left;
            prev_own  = act ? x  : prev_own;
        } else {
            prev_left = cl;
            prev_own  = x;
        }
    }
}

__global__ __launch_bounds__(512, 1)
void toeplitz_scan(const float* __restrict__ vin,   // inputs (L, 256)
                   const float* __restrict__ dtin,  // dt     (L, 256)
                   float* __restrict__ out)         // (L, 256, 256)
{
    extern __shared__ float lds[];
    float* g_arr = lds + G_OFF;   // [GPAD]
    float* b_arr = lds + B_OFF;   // [GPAD]
    float* ring  = lds + R_OFF;   // [4][RSLOT][64], row-indexed slots

    const int ch  = blockIdx.x;
    const int tid = threadIdx.x;

    // ---- per-channel g[l], beta[l] (+ pad), 512 threads ----
    #pragma unroll
    for (int k = 0; k < LLEN / 512; ++k) {
        const int l = tid + 512 * k;
        const float d = dtin[l * NCHAN + ch];
        const float u = vin[l * NCHAN + ch];
        const float ic = 1.0f / (1.0f + 0.25f * d);
        g_arr[l] = (1.0f - 0.25f * d) * ic;
        b_arr[l] = d * u * ic;
    }
    if (tid < GPAD - LLEN) {
        g_arr[LLEN + tid] = 1.0f;
        b_arr[LLEN + tid] = 0.0f;
    }
    __syncthreads();

    const int wv = tid >> 6, lane = tid & 63;

    if (wv < 4) {
        // ======================= compute waves =======================
        const int w = wv;
        const bool w0    = (w == 0);
        const bool lane0 = (lane == 0);
        const int wskew  = w * SKEW;
        float* my_ring = ring + w * (RSLOT * 64);
        const float* lf_ring = ring + (w > 0 ? (w - 1) : 0) * (RSLOT * 64);
        float prev_own = 0.0f, prev_left = 0.0f;

        for (int c = 0; c < NCHUNK; ++c) {
            const int T0 = c * KCH;
            const int bl = T0 - wskew;          // lane0's row (mult of 32)
            if (bl >= 0 && bl <= 1056) {
                const bool fast = (bl >= 64) && (bl <= LLEN - KCH);
                if (w0) {
                    if (fast)
                        do_chunk<true, false>(T0, bl, lane, lane0, g_arr,
                                              b_arr, my_ring, prev_own, prev_left);
                    else
                        do_chunk<true, true>(T0, bl, lane, lane0, g_arr,
                                             b_arr, my_ring, prev_own, prev_left);
                } else {
                    if (fast)
                        do_chunk<false, false>(T0, bl, lane, lane0, g_arr,
                                               lf_ring, my_ring, prev_own, prev_left);
                    else
                        do_chunk<false, true>(T0, bl, lane, lane0, g_arr,
                                              lf_ring, my_ring, prev_own, prev_left);
                }
            }
            lds_barrier();
        }
    } else {
        // ======================== store waves ========================
        const int sw = wv - 4;                  // serves compute wave sw
        const float* sring = ring + sw * (RSLOT * 64);
        const int rq = lane >> 4;               // row within 4-row group
        const int cq = (lane & 15) << 2;        // col-quad start
        float* const out_fl =
            out + (size_t)(ch * 256 + sw * 64 + cq);
        const int lag = sw * SKEW + 96;         // F = T0 - lag

        for (int c = 0; c < NCHUNK; ++c) {
            const int F = c * KCH - lag;
            if (F >= 0 && F <= LLEN - KCH) {
                const float* rb = sring + ((F & (RSLOT - 1)) << 6) + cq;
                f32x4 v[8];
                #pragma unroll
                for (int q = 0; q < 8; ++q)
                    v[q] = *reinterpret_cast<const f32x4*>(rb + ((4*q + rq) << 6));
                float* ob = out_fl + (size_t)(F + rq) * (NCHAN * 256);
                #pragma unroll
                for (int q = 0; q < 8; ++q) {
                    __builtin_nontemporal_store(v[q], reinterpret_cast<f32x4*>(ob));
                    ob += (size_t)4 * (NCHAN * 256);
                }
            }
            lds_barrier();
        }
    }
}

} // namespace

extern "C" void kernel_launch(void* const* d_in, const int* in_sizes, int n_in,
                              void* d_out, int out_size, void* d_ws, size_t ws_size,
                              hipStream_t stream) {
    (void)in_sizes; (void)n_in; (void)d_ws; (void)ws_size; (void)out_size;
    const float* vin  = (const float*)d_in[0];   // "inputs"
    const float* dtin = (const float*)d_in[1];   // "dt"
    float* out = (float*)d_out;

    (void)hipFuncSetAttribute(reinterpret_cast<const void*>(toeplitz_scan),
                              hipFuncAttributeMaxDynamicSharedMemorySize,
                              (int)LDS_BYTES);

    toeplitz_scan<<<NCHAN, 512, LDS_BYTES, stream>>>(vin, dtin, out);
}